// Round 9
// baseline (8967.662 us; speedup 1.0000x reference)
//
#include <hip/hip_runtime.h>

typedef __attribute__((ext_vector_type(8))) short bf16x8;
typedef __attribute__((ext_vector_type(4))) float f32x4;

union FU { unsigned int u[4]; uint4 q; bf16x8 v; };

__device__ inline unsigned int cvt_pk(float lo, float hi) {
    unsigned int r;
    asm("v_cvt_pk_bf16_f32 %0, %1, %2" : "=v"(r) : "v"(lo), "v"(hi));
    return r;
}

// tanh(x) = 1 - 2/(e^{2x}+1) = 1 - 2/(2^(x*2log2e)+1).
// exp2f is compiler-modeled (hazard-safe); one mul replaces add+mul of __expf(x+x).
#define TWO_LOG2E 2.8853900817779268f
__device__ inline float tanh_fast(float x) {
    float e = exp2f(x * TWO_LOG2E);
    return fmaf(-2.f, __builtin_amdgcn_rcpf(e + 1.f), 1.f);
}

// Sum lane l with lane l^32 on the VALU pipe (R5-proven).
__device__ inline float xor32_add(float p) {
    float c = p;
    asm("v_permlane32_swap_b32 %0, %1" : "+v"(c), "+v"(p));
    return p + c;
}

// Barrier that waits ONLY for LDS ops (lgkmcnt) — global stores stay in flight.
// All cross-wave dataflow in the loop is through LDS, so vmcnt drain is a false
// dependency created by __syncthreads' full-drain semantics.
__device__ inline void lds_barrier() {
    asm volatile("s_waitcnt lgkmcnt(0)\n\ts_barrier" ::: "memory");
}

#define TS 1000
#define ROWU 33            // uint4 granules per h1 row (512B + 16B pad)
#define P2ROW 208          // part2 row bytes: 8x16 (hi quads) + 8x8 (lo pairs) + pad

// R9 = R8 (validated) + lgkm-only barriers + rotated output wave + exp2f tanh.
__global__ __launch_bounds__(512, 4)
void node_ode_kernel(const float* __restrict__ Ig, const float* __restrict__ tg,
                     const float* __restrict__ W1g, const float* __restrict__ b1g,
                     const float* __restrict__ W2g, const float* __restrict__ b2g,
                     const float* __restrict__ W3g, const float* __restrict__ b3g,
                     float* __restrict__ outp)
{
    __shared__ __align__(16) uint4 h1q[16 * ROWU];     // 8448 B
    __shared__ __align__(16) char part2[16 * P2ROW];   // 3328 B
    __shared__ float dtss[TS - 1];                     // 3996 B

    const int tid  = threadIdx.x;
    const int lane = tid & 63;
    const int wv   = tid >> 6;       // 0..7
    const int nb   = lane & 15;      // batch row in tile
    const int g4   = lane >> 4;      // 0..3
    const int bb0  = blockIdx.x * 16;

    const int wbase = nb * ROWU + wv * 4 + g4;   // stage-A write slot (uint4)
    const int rbase = nb * ROWU + g4;            // stage-B read base (+ks*4)
    char* const prow = part2 + nb * P2ROW;

    for (int i = tid; i < TS - 1; i += 512) dtss[i] = tg[i + 1] - tg[i];

    const float b30 = b3g[0], b31 = b3g[1], b32 = b3g[2];

    // b2 for the unpermuted W2 channel map: acc0 ch = wv*32+4g4+r, acc1 = +16
    float4 b2r0 = *(const float4*)&b2g[wv * 32 + g4 * 4];
    float4 b2r1 = *(const float4*)&b2g[wv * 32 + 16 + g4 * 4];

    // ---- per-thread RK4 state ----
    float y00 = Ig[(bb0 + nb) * 3 + 0];
    float y01 = Ig[(bb0 + nb) * 3 + 1];
    float y02 = Ig[(bb0 + nb) * 3 + 2];
    if (tid < 16) {
        size_t o = (size_t)(bb0 + tid) * (TS * 3);
        outp[o + 0] = y00; outp[o + 1] = y01; outp[o + 2] = y02;
    }

    // ---- W2 persistent A-frags (unpermuted cols, R8 VERBATIM) ----
    bf16x8 w2f[2][8];
    {
        const int ncb = wv * 32 + nb;
        #pragma unroll
        for (int mt = 0; mt < 2; ++mt) {
            #pragma unroll
            for (int ks = 0; ks < 8; ++ks) {
                FU f;
                #pragma unroll
                for (int jj = 0; jj < 4; ++jj) {
                    int k0 = ks * 32 + g4 * 8 + jj * 2;
                    f.u[jj] = cvt_pk(W2g[(size_t)k0 * 256 + ncb + mt * 16],
                                     W2g[(size_t)(k0 + 1) * 256 + ncb + mt * 16]);
                }
                w2f[mt][ks] = f.v;
            }
        }
    }

    // ---- W1 persistent A-frags (permuted cols, split precision, R8 VERBATIM) ----
    bf16x8 w1a[2];
    {
        const int colb = wv * 32 + ((nb >> 2) << 3) + (nb & 3);
        #pragma unroll
        for (int mt = 0; mt < 2; ++mt) {
            const int col = colb + mt * 4;
            float w0 = W1g[col], w1 = W1g[256 + col], w2 = W1g[512 + col];
            float bb = b1g[col];
            FU f;
            if (g4 == 0) {
                f.u[0] = cvt_pk(w0, w1);
                f.u[1] = cvt_pk(w2, w0);
                f.u[2] = cvt_pk(w1, w2);
                f.u[3] = cvt_pk(bb, 0.f);
            } else if (g4 == 1) {
                unsigned int p01 = cvt_pk(w0, w1);
                unsigned int p2x = cvt_pk(w2, 0.f);
                float w0l = w0 - __uint_as_float(p01 << 16);
                float w1l = w1 - __uint_as_float(p01 & 0xFFFF0000u);
                float w2l = w2 - __uint_as_float(p2x << 16);
                f.u[0] = cvt_pk(w0l, w1l);
                f.u[1] = cvt_pk(w2l, 0.f);
                f.u[2] = 0u; f.u[3] = 0u;
            } else {
                f.u[0] = f.u[1] = f.u[2] = f.u[3] = 0u;
            }
            w1a[mt] = f.v;
        }
    }

    // ---- W3 persistent A-frag (R8 VERBATIM): rows 0-2 hi, 3-5 lo ----
    bf16x8 w3a;
    {
        FU f; f.u[0] = f.u[1] = f.u[2] = f.u[3] = 0u;
        if (nb < 6) {
            const int d = (nb < 3) ? nb : nb - 3;
            float w[8];
            #pragma unroll
            for (int j = 0; j < 8; ++j) {
                int ch = (j < 4) ? (wv * 32 + 4 * g4 + j)
                                 : (wv * 32 + 16 + 4 * g4 + (j - 4));
                w[j] = W3g[ch * 3 + d];
            }
            #pragma unroll
            for (int p = 0; p < 4; ++p) {
                unsigned int hp = cvt_pk(w[2 * p], w[2 * p + 1]);
                if (nb < 3) {
                    f.u[p] = hp;
                } else {
                    float l0 = w[2 * p]     - __uint_as_float(hp << 16);
                    float l1 = w[2 * p + 1] - __uint_as_float(hp & 0xFFFF0000u);
                    f.u[p] = cvt_pk(l0, l1);
                }
            }
        }
        w3a = f.v;
    }
    __syncthreads();   // init barrier: full drain, once

    auto EVAL = [&](float ycx, float ycy, float ycz,
                    float& kkx, float& kky, float& kkz) {
        // stage A: split-precision W1 mfma, one b128 write
        {
            unsigned int u01  = cvt_pk(ycx, ycy);
            float yl0 = ycx - __uint_as_float(u01 << 16);
            float yl1 = ycy - __uint_as_float(u01 & 0xFFFF0000u);
            unsigned int u2l0 = cvt_pk(ycz, yl0);
            float yl2 = ycz - __uint_as_float(u2l0 << 16);
            unsigned int ull  = cvt_pk(yl1, yl2);
            FU bf;
            if (g4 == 0) {
                bf.u[0] = u01; bf.u[1] = u2l0; bf.u[2] = ull; bf.u[3] = 0x00003f80u;
            } else if (g4 == 1) {
                bf.u[0] = u01; bf.u[1] = u2l0 & 0x0000FFFFu; bf.u[2] = 0u; bf.u[3] = 0u;
            } else {
                bf.u[0] = bf.u[1] = bf.u[2] = bf.u[3] = 0u;
            }
            f32x4 dA = {0.f, 0.f, 0.f, 0.f};
            f32x4 dB = {0.f, 0.f, 0.f, 0.f};
            dA = __builtin_amdgcn_mfma_f32_16x16x32_bf16(w1a[0], bf.v, dA, 0, 0, 0);
            dB = __builtin_amdgcn_mfma_f32_16x16x32_bf16(w1a[1], bf.v, dB, 0, 0, 0);
            uint4 wq;
            wq.x = cvt_pk(tanh_fast(dA[0]), tanh_fast(dA[1]));
            wq.y = cvt_pk(tanh_fast(dA[2]), tanh_fast(dA[3]));
            wq.z = cvt_pk(tanh_fast(dB[0]), tanh_fast(dB[1]));
            wq.w = cvt_pk(tanh_fast(dB[2]), tanh_fast(dB[3]));
            h1q[wbase] = wq;
        }
        lds_barrier();

        // stage B: 16 W2 mfma + 8 tanh + pack + 1 W3 mfma + partial write
        {
            f32x4 acc0 = {b2r0.x, b2r0.y, b2r0.z, b2r0.w};
            f32x4 acc1 = {b2r1.x, b2r1.y, b2r1.z, b2r1.w};
            #pragma unroll
            for (int ks = 0; ks < 8; ++ks) {
                FU tm; tm.q = h1q[rbase + ks * 4];
                acc0 = __builtin_amdgcn_mfma_f32_16x16x32_bf16(w2f[0][ks], tm.v, acc0, 0, 0, 0);
                acc1 = __builtin_amdgcn_mfma_f32_16x16x32_bf16(w2f[1][ks], tm.v, acc1, 0, 0, 0);
            }
            FU pb;
            pb.u[0] = cvt_pk(tanh_fast(acc0[0]), tanh_fast(acc0[1]));
            pb.u[1] = cvt_pk(tanh_fast(acc0[2]), tanh_fast(acc0[3]));
            pb.u[2] = cvt_pk(tanh_fast(acc1[0]), tanh_fast(acc1[1]));
            pb.u[3] = cvt_pk(tanh_fast(acc1[2]), tanh_fast(acc1[3]));
            f32x4 pd = {0.f, 0.f, 0.f, 0.f};
            pd = __builtin_amdgcn_mfma_f32_16x16x32_bf16(w3a, pb.v, pd, 0, 0, 0);
            if (g4 == 0)
                *(float4*)(prow + wv * 16) = make_float4(pd[0], pd[1], pd[2], pd[3]);
            else if (g4 == 1)
                *(float2*)(prow + 128 + wv * 8) = make_float2(pd[0], pd[1]);
        }
        lds_barrier();

        // combine: 3 reads distributed over g4 + xor16 + xor32
        {
            float4 q1 = *(const float4*)(prow + g4 * 16);
            float4 q2 = *(const float4*)(prow + 64 + g4 * 16);
            float4 q3 = *(const float4*)(prow + 128 + g4 * 16);
            float k0 = (q1.x + q2.x) + (q1.w + q2.w);
            float k1 = (q1.y + q2.y) + (q3.x + q3.z);
            float k2 = (q1.z + q2.z) + (q3.y + q3.w);
            k0 += __shfl_xor(k0, 16); k1 += __shfl_xor(k1, 16); k2 += __shfl_xor(k2, 16);
            kkx = xor32_add(k0) + b30;
            kky = xor32_add(k1) + b31;
            kkz = xor32_add(k2) + b32;
        }
    };

    for (int t = 0; t < TS - 1; ++t) {
        const float dtc = dtss[t];
        const float hh = 0.5f * dtc;
        float k1x, k1y, k1z, k2x, k2y, k2z, k3x, k3y, k3z, k4x, k4y, k4z;
        EVAL(y00, y01, y02, k1x, k1y, k1z);
        EVAL(fmaf(hh, k1x, y00), fmaf(hh, k1y, y01), fmaf(hh, k1z, y02),
             k2x, k2y, k2z);
        EVAL(fmaf(hh, k2x, y00), fmaf(hh, k2y, y01), fmaf(hh, k2z, y02),
             k3x, k3y, k3z);
        EVAL(fmaf(dtc, k3x, y00), fmaf(dtc, k3y, y01), fmaf(dtc, k3z, y02),
             k4x, k4y, k4z);
        const float s = dtc * (1.f / 6.f);
        y00 = fmaf(s, (k1x + k4x) + 2.f * (k2x + k3x), y00);
        y01 = fmaf(s, (k1y + k4y) + 2.f * (k2y + k3y), y01);
        y02 = fmaf(s, (k1z + k4z) + 2.f * (k2z + k3z), y02);
        // rotate the storing wave so outstanding global stores never gate a barrier
        if ((wv == (t & 7)) && lane < 16) {
            size_t o = (size_t)(bb0 + nb) * (TS * 3) + (size_t)(t + 1) * 3;
            outp[o + 0] = y00; outp[o + 1] = y01; outp[o + 2] = y02;
        }
    }
}

extern "C" void kernel_launch(void* const* d_in, const int* in_sizes, int n_in,
                              void* d_out, int out_size, void* d_ws, size_t ws_size,
                              hipStream_t stream) {
    (void)in_sizes; (void)n_in; (void)d_ws; (void)ws_size; (void)out_size;
    const float* Ig  = (const float*)d_in[0];
    const float* tg  = (const float*)d_in[1];
    const float* W1g = (const float*)d_in[2];
    const float* b1g = (const float*)d_in[3];
    const float* W2g = (const float*)d_in[4];
    const float* b2g = (const float*)d_in[5];
    const float* W3g = (const float*)d_in[6];
    const float* b3g = (const float*)d_in[7];
    float* outp = (float*)d_out;

    dim3 grid(512), block(512);
    hipLaunchKernelGGL(node_ode_kernel, grid, block, 0, stream,
                       Ig, tg, W1g, b1g, W2g, b2g, W3g, b3g, outp);
}

// Round 10
// 7170.616 us; speedup vs baseline: 1.2506x; 1.2506x over previous
//
#include <hip/hip_runtime.h>

typedef __attribute__((ext_vector_type(8))) short bf16x8;
typedef __attribute__((ext_vector_type(4))) float f32x4;

union FU { unsigned int u[4]; uint4 q; bf16x8 v; };

__device__ inline unsigned int cvt_pk(float lo, float hi) {
    unsigned int r;
    asm("v_cvt_pk_bf16_f32 %0, %1, %2" : "=v"(r) : "v"(lo), "v"(hi));
    return r;
}

// tanh(x) = 1 - 2/(2^(x*2log2e)+1). Native exp2 builtin = single v_exp_f32,
// compiler-modeled (hazard-safe). R9's exp2f() was OCML's ACCURATE exp2
// (range fixup, ~5 extra VALU/call) -> +26% VALU cycles -> the regression.
#define TWO_LOG2E 2.8853900817779268f
__device__ inline float tanh_fast(float x) {
#if __has_builtin(__builtin_amdgcn_exp2f)
    float e = __builtin_amdgcn_exp2f(x * TWO_LOG2E);
#else
    float e = __expf(x + x);   // R8-proven fallback (native: mul+v_exp)
#endif
    return fmaf(-2.f, __builtin_amdgcn_rcpf(e + 1.f), 1.f);
}

// Sum lane l with lane l^32 on the VALU pipe (R5-proven).
__device__ inline float xor32_add(float p) {
    float c = p;
    asm("v_permlane32_swap_b32 %0, %1" : "+v"(c), "+v"(p));
    return p + c;
}

// Barrier waiting ONLY on LDS ops — in-flight global stores don't gate it.
// (R9 showed this bundle is >= neutral; all cross-wave dataflow is LDS.)
__device__ inline void lds_barrier() {
    asm volatile("s_waitcnt lgkmcnt(0)\n\ts_barrier" ::: "memory");
}

#define TS 1000
#define ROWU 33            // uint4 granules per h1 row (512B + 16B pad)
#define P2ROW 208          // part2 row bytes: 8x16 (hi quads) + 8x8 (lo pairs) + pad

// R10 = R9 with native-exp2 tanh (single-variable fix of the R9 regression).
__global__ __launch_bounds__(512, 4)
void node_ode_kernel(const float* __restrict__ Ig, const float* __restrict__ tg,
                     const float* __restrict__ W1g, const float* __restrict__ b1g,
                     const float* __restrict__ W2g, const float* __restrict__ b2g,
                     const float* __restrict__ W3g, const float* __restrict__ b3g,
                     float* __restrict__ outp)
{
    __shared__ __align__(16) uint4 h1q[16 * ROWU];     // 8448 B
    __shared__ __align__(16) char part2[16 * P2ROW];   // 3328 B
    __shared__ float dtss[TS - 1];                     // 3996 B

    const int tid  = threadIdx.x;
    const int lane = tid & 63;
    const int wv   = tid >> 6;       // 0..7
    const int nb   = lane & 15;      // batch row in tile
    const int g4   = lane >> 4;      // 0..3
    const int bb0  = blockIdx.x * 16;

    const int wbase = nb * ROWU + wv * 4 + g4;   // stage-A write slot (uint4)
    const int rbase = nb * ROWU + g4;            // stage-B read base (+ks*4)
    char* const prow = part2 + nb * P2ROW;

    for (int i = tid; i < TS - 1; i += 512) dtss[i] = tg[i + 1] - tg[i];

    const float b30 = b3g[0], b31 = b3g[1], b32 = b3g[2];

    // b2 for the unpermuted W2 channel map: acc0 ch = wv*32+4g4+r, acc1 = +16
    float4 b2r0 = *(const float4*)&b2g[wv * 32 + g4 * 4];
    float4 b2r1 = *(const float4*)&b2g[wv * 32 + 16 + g4 * 4];

    // ---- per-thread RK4 state ----
    float y00 = Ig[(bb0 + nb) * 3 + 0];
    float y01 = Ig[(bb0 + nb) * 3 + 1];
    float y02 = Ig[(bb0 + nb) * 3 + 2];
    if (tid < 16) {
        size_t o = (size_t)(bb0 + tid) * (TS * 3);
        outp[o + 0] = y00; outp[o + 1] = y01; outp[o + 2] = y02;
    }

    // ---- W2 persistent A-frags (unpermuted cols, R8 VERBATIM) ----
    bf16x8 w2f[2][8];
    {
        const int ncb = wv * 32 + nb;
        #pragma unroll
        for (int mt = 0; mt < 2; ++mt) {
            #pragma unroll
            for (int ks = 0; ks < 8; ++ks) {
                FU f;
                #pragma unroll
                for (int jj = 0; jj < 4; ++jj) {
                    int k0 = ks * 32 + g4 * 8 + jj * 2;
                    f.u[jj] = cvt_pk(W2g[(size_t)k0 * 256 + ncb + mt * 16],
                                     W2g[(size_t)(k0 + 1) * 256 + ncb + mt * 16]);
                }
                w2f[mt][ks] = f.v;
            }
        }
    }

    // ---- W1 persistent A-frags (permuted cols, split precision, R8 VERBATIM) ----
    bf16x8 w1a[2];
    {
        const int colb = wv * 32 + ((nb >> 2) << 3) + (nb & 3);
        #pragma unroll
        for (int mt = 0; mt < 2; ++mt) {
            const int col = colb + mt * 4;
            float w0 = W1g[col], w1 = W1g[256 + col], w2 = W1g[512 + col];
            float bb = b1g[col];
            FU f;
            if (g4 == 0) {
                f.u[0] = cvt_pk(w0, w1);
                f.u[1] = cvt_pk(w2, w0);
                f.u[2] = cvt_pk(w1, w2);
                f.u[3] = cvt_pk(bb, 0.f);
            } else if (g4 == 1) {
                unsigned int p01 = cvt_pk(w0, w1);
                unsigned int p2x = cvt_pk(w2, 0.f);
                float w0l = w0 - __uint_as_float(p01 << 16);
                float w1l = w1 - __uint_as_float(p01 & 0xFFFF0000u);
                float w2l = w2 - __uint_as_float(p2x << 16);
                f.u[0] = cvt_pk(w0l, w1l);
                f.u[1] = cvt_pk(w2l, 0.f);
                f.u[2] = 0u; f.u[3] = 0u;
            } else {
                f.u[0] = f.u[1] = f.u[2] = f.u[3] = 0u;
            }
            w1a[mt] = f.v;
        }
    }

    // ---- W3 persistent A-frag (R8 VERBATIM): rows 0-2 hi, 3-5 lo ----
    bf16x8 w3a;
    {
        FU f; f.u[0] = f.u[1] = f.u[2] = f.u[3] = 0u;
        if (nb < 6) {
            const int d = (nb < 3) ? nb : nb - 3;
            float w[8];
            #pragma unroll
            for (int j = 0; j < 8; ++j) {
                int ch = (j < 4) ? (wv * 32 + 4 * g4 + j)
                                 : (wv * 32 + 16 + 4 * g4 + (j - 4));
                w[j] = W3g[ch * 3 + d];
            }
            #pragma unroll
            for (int p = 0; p < 4; ++p) {
                unsigned int hp = cvt_pk(w[2 * p], w[2 * p + 1]);
                if (nb < 3) {
                    f.u[p] = hp;
                } else {
                    float l0 = w[2 * p]     - __uint_as_float(hp << 16);
                    float l1 = w[2 * p + 1] - __uint_as_float(hp & 0xFFFF0000u);
                    f.u[p] = cvt_pk(l0, l1);
                }
            }
        }
        w3a = f.v;
    }
    __syncthreads();   // init barrier: full drain, once

    auto EVAL = [&](float ycx, float ycy, float ycz,
                    float& kkx, float& kky, float& kkz) {
        // stage A: split-precision W1 mfma, one b128 write
        {
            unsigned int u01  = cvt_pk(ycx, ycy);
            float yl0 = ycx - __uint_as_float(u01 << 16);
            float yl1 = ycy - __uint_as_float(u01 & 0xFFFF0000u);
            unsigned int u2l0 = cvt_pk(ycz, yl0);
            float yl2 = ycz - __uint_as_float(u2l0 << 16);
            unsigned int ull  = cvt_pk(yl1, yl2);
            FU bf;
            if (g4 == 0) {
                bf.u[0] = u01; bf.u[1] = u2l0; bf.u[2] = ull; bf.u[3] = 0x00003f80u;
            } else if (g4 == 1) {
                bf.u[0] = u01; bf.u[1] = u2l0 & 0x0000FFFFu; bf.u[2] = 0u; bf.u[3] = 0u;
            } else {
                bf.u[0] = bf.u[1] = bf.u[2] = bf.u[3] = 0u;
            }
            f32x4 dA = {0.f, 0.f, 0.f, 0.f};
            f32x4 dB = {0.f, 0.f, 0.f, 0.f};
            dA = __builtin_amdgcn_mfma_f32_16x16x32_bf16(w1a[0], bf.v, dA, 0, 0, 0);
            dB = __builtin_amdgcn_mfma_f32_16x16x32_bf16(w1a[1], bf.v, dB, 0, 0, 0);
            uint4 wq;
            wq.x = cvt_pk(tanh_fast(dA[0]), tanh_fast(dA[1]));
            wq.y = cvt_pk(tanh_fast(dA[2]), tanh_fast(dA[3]));
            wq.z = cvt_pk(tanh_fast(dB[0]), tanh_fast(dB[1]));
            wq.w = cvt_pk(tanh_fast(dB[2]), tanh_fast(dB[3]));
            h1q[wbase] = wq;
        }
        lds_barrier();

        // stage B: 16 W2 mfma + 8 tanh + pack + 1 W3 mfma + partial write
        {
            f32x4 acc0 = {b2r0.x, b2r0.y, b2r0.z, b2r0.w};
            f32x4 acc1 = {b2r1.x, b2r1.y, b2r1.z, b2r1.w};
            #pragma unroll
            for (int ks = 0; ks < 8; ++ks) {
                FU tm; tm.q = h1q[rbase + ks * 4];
                acc0 = __builtin_amdgcn_mfma_f32_16x16x32_bf16(w2f[0][ks], tm.v, acc0, 0, 0, 0);
                acc1 = __builtin_amdgcn_mfma_f32_16x16x32_bf16(w2f[1][ks], tm.v, acc1, 0, 0, 0);
            }
            FU pb;
            pb.u[0] = cvt_pk(tanh_fast(acc0[0]), tanh_fast(acc0[1]));
            pb.u[1] = cvt_pk(tanh_fast(acc0[2]), tanh_fast(acc0[3]));
            pb.u[2] = cvt_pk(tanh_fast(acc1[0]), tanh_fast(acc1[1]));
            pb.u[3] = cvt_pk(tanh_fast(acc1[2]), tanh_fast(acc1[3]));
            f32x4 pd = {0.f, 0.f, 0.f, 0.f};
            pd = __builtin_amdgcn_mfma_f32_16x16x32_bf16(w3a, pb.v, pd, 0, 0, 0);
            if (g4 == 0)
                *(float4*)(prow + wv * 16) = make_float4(pd[0], pd[1], pd[2], pd[3]);
            else if (g4 == 1)
                *(float2*)(prow + 128 + wv * 8) = make_float2(pd[0], pd[1]);
        }
        lds_barrier();

        // combine: 3 reads distributed over g4 + xor16 + xor32
        {
            float4 q1 = *(const float4*)(prow + g4 * 16);
            float4 q2 = *(const float4*)(prow + 64 + g4 * 16);
            float4 q3 = *(const float4*)(prow + 128 + g4 * 16);
            float k0 = (q1.x + q2.x) + (q1.w + q2.w);
            float k1 = (q1.y + q2.y) + (q3.x + q3.z);
            float k2 = (q1.z + q2.z) + (q3.y + q3.w);
            k0 += __shfl_xor(k0, 16); k1 += __shfl_xor(k1, 16); k2 += __shfl_xor(k2, 16);
            kkx = xor32_add(k0) + b30;
            kky = xor32_add(k1) + b31;
            kkz = xor32_add(k2) + b32;
        }
    };

    for (int t = 0; t < TS - 1; ++t) {
        const float dtc = dtss[t];
        const float hh = 0.5f * dtc;
        float k1x, k1y, k1z, k2x, k2y, k2z, k3x, k3y, k3z, k4x, k4y, k4z;
        EVAL(y00, y01, y02, k1x, k1y, k1z);
        EVAL(fmaf(hh, k1x, y00), fmaf(hh, k1y, y01), fmaf(hh, k1z, y02),
             k2x, k2y, k2z);
        EVAL(fmaf(hh, k2x, y00), fmaf(hh, k2y, y01), fmaf(hh, k2z, y02),
             k3x, k3y, k3z);
        EVAL(fmaf(dtc, k3x, y00), fmaf(dtc, k3y, y01), fmaf(dtc, k3z, y02),
             k4x, k4y, k4z);
        const float s = dtc * (1.f / 6.f);
        y00 = fmaf(s, (k1x + k4x) + 2.f * (k2x + k3x), y00);
        y01 = fmaf(s, (k1y + k4y) + 2.f * (k2y + k3y), y01);
        y02 = fmaf(s, (k1z + k4z) + 2.f * (k2z + k3z), y02);
        // rotate the storing wave so outstanding global stores spread across waves
        if ((wv == (t & 7)) && lane < 16) {
            size_t o = (size_t)(bb0 + nb) * (TS * 3) + (size_t)(t + 1) * 3;
            outp[o + 0] = y00; outp[o + 1] = y01; outp[o + 2] = y02;
        }
    }
}

extern "C" void kernel_launch(void* const* d_in, const int* in_sizes, int n_in,
                              void* d_out, int out_size, void* d_ws, size_t ws_size,
                              hipStream_t stream) {
    (void)in_sizes; (void)n_in; (void)d_ws; (void)ws_size; (void)out_size;
    const float* Ig  = (const float*)d_in[0];
    const float* tg  = (const float*)d_in[1];
    const float* W1g = (const float*)d_in[2];
    const float* b1g = (const float*)d_in[3];
    const float* W2g = (const float*)d_in[4];
    const float* b2g = (const float*)d_in[5];
    const float* W3g = (const float*)d_in[6];
    const float* b3g = (const float*)d_in[7];
    float* outp = (float*)d_out;

    dim3 grid(512), block(512);
    hipLaunchKernelGGL(node_ode_kernel, grid, block, 0, stream,
                       Ig, tg, W1g, b1g, W2g, b2g, W3g, b3g, outp);
}